// Round 5
// baseline (1451.252 us; speedup 1.0000x reference)
//
#include <hip/hip_runtime.h>
#include <cstdint>
#include <cstddef>

#define B_   32
#define LQ   2048
#define LK   2048
#define DK   64
#define DV   64
#define TQ   16
#define LDP  2056   // padded P row length in bf16 elems; byte stride 4112 (16B-aligned, 2-way-max LDS conflicts)

typedef short bf16x8 __attribute__((ext_vector_type(8)));
typedef float f32x4  __attribute__((ext_vector_type(4)));

// exp(x/8) = exp2(x * log2(e)/8)
#define KSCALE 0.1803368801111204f

__device__ __forceinline__ short f2bf(float f) {          // round-to-nearest-even fp32->bf16
  unsigned u = __builtin_bit_cast(unsigned, f);
  u += 0x7fffu + ((u >> 16) & 1u);
  return (short)(u >> 16);
}

__device__ __forceinline__ bf16x8 pack8(float4 a, float4 b) {
  bf16x8 r;
  r[0]=f2bf(a.x); r[1]=f2bf(a.y); r[2]=f2bf(a.z); r[3]=f2bf(a.w);
  r[4]=f2bf(b.x); r[5]=f2bf(b.y); r[6]=f2bf(b.z); r[7]=f2bf(b.w);
  return r;
}

// ---------------------------------------------------------------------------
// Kernel A (read-dominated stream): QK^T + exp + mask -> rowsums only.
// Side products: 1-bit/elem mask bitmap (via __ballot) stashed in the `out`
// buffer (16.78 MB, exactly out's size; B consumes its own tile's bits into
// LDS before PV overwrites that region -> same-block ownership, race-free),
// and rowsum stashed at attn[row][0] (B reads it before overwriting the row).
// No LDS tile, no P storage -> high occupancy, mask NT-read stream dominates.
// ---------------------------------------------------------------------------
__global__ __launch_bounds__(512, 6) void rowsum_kernel(
    const float* __restrict__ q, const float* __restrict__ k,
    const int* __restrict__ mask, float* __restrict__ bmout,
    float* __restrict__ attn) {
  __shared__ float rowsum[TQ];

  const int tid  = threadIdx.x;
  const int wv   = tid >> 6;
  const int lane = tid & 63;
  const int quad = lane >> 4;
  const int l15  = lane & 15;
  const int b     = blockIdx.y;
  const int qbase = blockIdx.x * TQ;

  if (tid < TQ) rowsum[tid] = 0.0f;
  __syncthreads();

  const float* qr = q + ((size_t)b * LQ + qbase + l15) * DK + quad * 8;
  bf16x8 qa0 = pack8(*(const float4*)(qr),      *(const float4*)(qr + 4));
  bf16x8 qa1 = pack8(*(const float4*)(qr + 32), *(const float4*)(qr + 36));

  const float* kbase = k + (size_t)b * LK * DK + (size_t)l15 * DK + quad * 8;
  const int*   mbase = mask + ((size_t)b * LQ + qbase + quad * 4) * (size_t)LK + l15;
  unsigned long long* bmbase =
      (unsigned long long*)(bmout + ((size_t)b * LQ + qbase) * DV);
  const f32x4 z4 = {0.f, 0.f, 0.f, 0.f};

  float4 kp0, kp1, kp2, kp3;
  int mp0[4], mp1[4];
  {
    const float* kr = kbase + (size_t)wv * (16 * DK);
    kp0 = *(const float4*)(kr);      kp1 = *(const float4*)(kr + 4);
    kp2 = *(const float4*)(kr + 32); kp3 = *(const float4*)(kr + 36);
    const int* mr0 = mbase + wv * 16;
    const int* mr1 = mbase + (wv + 8) * 16;
    #pragma unroll
    for (int r = 0; r < 4; ++r) {
      mp0[r] = __builtin_nontemporal_load(mr0 + (size_t)r * LK);
      mp1[r] = __builtin_nontemporal_load(mr1 + (size_t)r * LK);
    }
  }
  float sum0[4] = {0,0,0,0};
  #pragma unroll 1
  for (int j = 0; j < 16; ++j) {
    float4 kc0 = kp0, kc1 = kp1, kc2 = kp2, kc3 = kp3;
    int mc[4];
    #pragma unroll
    for (int r = 0; r < 4; ++r) { mc[r] = mp0[r]; mp0[r] = mp1[r]; }
    const int ntc = wv + 8 * j;
    if (j < 15) {   // K prefetch depth 1 (L2-resident)
      const float* kr = kbase + (size_t)(ntc + 8) * (16 * DK);
      kp0 = *(const float4*)(kr);      kp1 = *(const float4*)(kr + 4);
      kp2 = *(const float4*)(kr + 32); kp3 = *(const float4*)(kr + 36);
    }
    if (j < 14) {   // mask prefetch depth 2 (HBM latency cover)
      const int* mr = mbase + (ntc + 16) * 16;
      #pragma unroll
      for (int r = 0; r < 4; ++r)
        mp1[r] = __builtin_nontemporal_load(mr + (size_t)r * LK);
    }
    bf16x8 kb0 = pack8(kc0, kc1);
    bf16x8 kb1 = pack8(kc2, kc3);
    f32x4 acc0 = __builtin_amdgcn_mfma_f32_16x16x32_bf16(qa0, kb0, z4, 0, 0, 0);
    acc0       = __builtin_amdgcn_mfma_f32_16x16x32_bf16(qa1, kb1, acc0, 0, 0, 0);
    // D[row=quad*4+r][col=l15]; ballot bit i = lane i's mask
    #pragma unroll
    for (int r = 0; r < 4; ++r) {
      const bool mm = (mc[r] != 0);
      unsigned long long bal = __ballot(mm);
      float p = mm ? 0.0f : __builtin_amdgcn_exp2f(acc0[r] * KSCALE);
      sum0[r] += p;
      if (lane == r) bmbase[(size_t)ntc * 4 + r] = bal;   // uniform value, 1 writer
    }
  }
  // quad-level (16-lane) reduction: each quad owns rows quad*4+r
  #pragma unroll
  for (int r = 0; r < 4; ++r) {
    float s0 = sum0[r];
    #pragma unroll
    for (int off = 1; off < 16; off <<= 1) s0 += __shfl_xor(s0, off);
    if (l15 == 0) atomicAdd(&rowsum[quad * 4 + r], s0);
  }
  __syncthreads();
  if (tid < TQ)
    attn[((size_t)b * LQ + qbase + tid) * (size_t)LK] = rowsum[tid];  // stash
}

// ---------------------------------------------------------------------------
// Kernel B (write-dominated stream): recompute QK^T (MFMA is ~free), mask via
// LDS-resident bitmap, normalize with precomputed rinv, and NT-stream f32 attn
// DIRECTLY from the compute loop (single pass, no staging, no round-trip).
// Normalized bf16 P kept in LDS for PV; 8-wave split-kt PV -> out (overwrites
// this tile's bitmap region, already consumed).
// ---------------------------------------------------------------------------
__global__ __launch_bounds__(512, 4) void attn_pv_kernel(
    const float* __restrict__ q, const float* __restrict__ k,
    const float* __restrict__ v, float* out, float* attn) {
  __shared__ short P[TQ][LDP];     // normalized p, bf16
  __shared__ uint2 BM[512];        // 4 KB bitmask tile
  __shared__ float rinv[TQ];
  __shared__ float Opart[TQ][68];  // PV partials from waves 4-7 (padded)

  const int tid  = threadIdx.x;
  const int wv   = tid >> 6;
  const int lane = tid & 63;
  const int quad = lane >> 4;
  const int l15  = lane & 15;
  const int b     = blockIdx.y;
  const int qbase = blockIdx.x * TQ;

  // consume this tile's bitmask + rowsum stash before any writes
  const uint2* bmg = (const uint2*)(out + ((size_t)b * LQ + qbase) * DV);
  BM[tid] = bmg[tid];
  if (tid < TQ)
    rinv[tid] = 1.0f / attn[((size_t)b * LQ + qbase + tid) * (size_t)LK];
  __syncthreads();

  float my_ri[4];
  #pragma unroll
  for (int r = 0; r < 4; ++r) my_ri[r] = rinv[quad * 4 + r];

  const float* qr = q + ((size_t)b * LQ + qbase + l15) * DK + quad * 8;
  bf16x8 qa0 = pack8(*(const float4*)(qr),      *(const float4*)(qr + 4));
  bf16x8 qa1 = pack8(*(const float4*)(qr + 32), *(const float4*)(qr + 36));

  const float* kbase = k + (size_t)b * LK * DK + (size_t)l15 * DK + quad * 8;
  float* abase = attn + ((size_t)b * LQ + qbase + quad * 4) * (size_t)LK + l15;
  const f32x4 z4 = {0.f, 0.f, 0.f, 0.f};

  float4 kp0, kp1, kp2, kp3;
  {
    const float* kr = kbase + (size_t)wv * (16 * DK);
    kp0 = *(const float4*)(kr);      kp1 = *(const float4*)(kr + 4);
    kp2 = *(const float4*)(kr + 32); kp3 = *(const float4*)(kr + 36);
  }
  #pragma unroll 1
  for (int j = 0; j < 16; ++j) {
    float4 kc0 = kp0, kc1 = kp1, kc2 = kp2, kc3 = kp3;
    const int ntc = wv + 8 * j;
    if (j < 15) {
      const float* kr = kbase + (size_t)(ntc + 8) * (16 * DK);
      kp0 = *(const float4*)(kr);      kp1 = *(const float4*)(kr + 4);
      kp2 = *(const float4*)(kr + 32); kp3 = *(const float4*)(kr + 36);
    }
    bf16x8 kb0 = pack8(kc0, kc1);
    bf16x8 kb1 = pack8(kc2, kc3);
    f32x4 acc0 = __builtin_amdgcn_mfma_f32_16x16x32_bf16(qa0, kb0, z4, 0, 0, 0);
    acc0       = __builtin_amdgcn_mfma_f32_16x16x32_bf16(qa1, kb1, acc0, 0, 0, 0);
    const int col = ntc * 16 + l15;
    float* ast = abase + ntc * 16;
    #pragma unroll
    for (int r = 0; r < 4; ++r) {
      uint2 wm = BM[ntc * 4 + r];
      unsigned ws = (lane & 32) ? wm.y : wm.x;
      const bool mm = (ws >> (lane & 31)) & 1u;
      float p = mm ? 0.0f
                   : __builtin_amdgcn_exp2f(acc0[r] * KSCALE) * my_ri[r];
      P[quad * 4 + r][col] = f2bf(p);
      __builtin_nontemporal_store(p, ast + (size_t)r * LK);   // final attn value
    }
  }
  __syncthreads();

  // ---- PV: all 8 waves; wave = (col-tile w, kt-half); combine via Opart ----
  const int w    = wv & 3;
  const int half = wv >> 2;
  const int ktb  = half * 32;
  const float* vbase = v + (size_t)b * LK * DV + w * 16 + l15;
  f32x4 o0 = z4;
  float fva[8], fvb[8];
  #pragma unroll
  for (int jj = 0; jj < 8; ++jj) {
    fva[jj] = vbase[(size_t)(ktb * 32 + quad * 8 + jj) * DV];
    fvb[jj] = vbase[(size_t)((ktb + 1) * 32 + quad * 8 + jj) * DV];
  }
  #pragma unroll 1
  for (int kt2 = 0; kt2 < 32; kt2 += 2) {
    const int kt = ktb + kt2;
    float fc[8];
    #pragma unroll
    for (int jj = 0; jj < 8; ++jj) fc[jj] = fva[jj];
    if (kt2 != 30) {
      #pragma unroll
      for (int jj = 0; jj < 8; ++jj)
        fva[jj] = vbase[(size_t)((kt + 2) * 32 + quad * 8 + jj) * DV];
    }
    bf16x8 bv0;
    #pragma unroll
    for (int jj = 0; jj < 8; ++jj) bv0[jj] = f2bf(fc[jj]);
    bf16x8 a0 = *(const bf16x8*)&P[l15][kt * 32 + quad * 8];
    o0 = __builtin_amdgcn_mfma_f32_16x16x32_bf16(a0, bv0, o0, 0, 0, 0);

    #pragma unroll
    for (int jj = 0; jj < 8; ++jj) fc[jj] = fvb[jj];
    if (kt2 != 30) {
      #pragma unroll
      for (int jj = 0; jj < 8; ++jj)
        fvb[jj] = vbase[(size_t)((kt + 3) * 32 + quad * 8 + jj) * DV];
    }
    bf16x8 bv1;
    #pragma unroll
    for (int jj = 0; jj < 8; ++jj) bv1[jj] = f2bf(fc[jj]);
    bf16x8 a1 = *(const bf16x8*)&P[l15][(kt + 1) * 32 + quad * 8];
    o0 = __builtin_amdgcn_mfma_f32_16x16x32_bf16(a1, bv1, o0, 0, 0, 0);
  }
  if (half == 1) {
    #pragma unroll
    for (int r = 0; r < 4; ++r) Opart[quad * 4 + r][w * 16 + l15] = o0[r];
  }
  __syncthreads();
  if (half == 0) {
    #pragma unroll
    for (int r = 0; r < 4; ++r) {
      const int row0 = quad * 4 + r;
      out[((size_t)b * LQ + qbase + row0) * DV + w * 16 + l15] =
          o0[r] + Opart[row0][w * 16 + l15];    // P already normalized
    }
  }
}

extern "C" void kernel_launch(void* const* d_in, const int* in_sizes, int n_in,
                              void* d_out, int out_size, void* d_ws, size_t ws_size,
                              hipStream_t stream) {
  (void)in_sizes; (void)n_in; (void)out_size; (void)d_ws; (void)ws_size;
  const float* q    = (const float*)d_in[0];
  const float* k    = (const float*)d_in[1];
  const float* v    = (const float*)d_in[2];
  const int*   mask = (const int*)d_in[3];
  float* out  = (float*)d_out;
  float* attn = out + (size_t)B_ * LQ * DV;   // outputs concatenated: (out, attn)
  dim3 grid(LQ / TQ, B_);
  rowsum_kernel<<<grid, 512, 0, stream>>>(q, k, mask, out, attn);
  attn_pv_kernel<<<grid, 512, 0, stream>>>(q, k, v, out, attn);
}